// Round 1
// baseline (2571.491 us; speedup 1.0000x reference)
//
#include <hip/hip_runtime.h>

#define N_PTS   16384
#define NPOINT  1024
#define NSAMPLE 64
// Match JAX: radius*radius computed in python f64 (0.3*0.3), then cast to f32 at compare
#define R2 ((float)(0.3 * 0.3))

// ---------------------------------------------------------------------------
// Kernel 1: furthest point sampling. One block per batch, 1024 threads.
// Each thread owns 16 points (xyz + mindist) in registers, statically indexed.
// Writes new_xyz = xyz[fps_idx] directly to d_out (first 4*1024*3 floats).
// ---------------------------------------------------------------------------
__global__ __launch_bounds__(1024, 1) void fps_kernel(
    const float* __restrict__ xyz, float* __restrict__ out_newxyz) {
    const int b = blockIdx.x;
    const int t = threadIdx.x;
    const float* X = xyz + (size_t)b * N_PTS * 3;

    float px[16], py[16], pz[16], md[16];
#pragma unroll
    for (int j = 0; j < 16; ++j) {
        int n = j * 1024 + t;
        px[j] = X[3 * n];
        py[j] = X[3 * n + 1];
        pz[j] = X[3 * n + 2];
        md[j] = 1e10f;
    }

    // first selected point is index 0
    float lx = X[0], ly = X[1], lz = X[2];
    if (t == 0) {
        out_newxyz[b * NPOINT * 3 + 0] = lx;
        out_newxyz[b * NPOINT * 3 + 1] = ly;
        out_newxyz[b * NPOINT * 3 + 2] = lz;
    }

    __shared__ float s_val[16];
    __shared__ int   s_idx[16];

    for (int i = 1; i < NPOINT; ++i) {
        float bv = -1.0f;
        int   bi = 0;
#pragma unroll
        for (int j = 0; j < 16; ++j) {
            float dx = px[j] - lx, dy = py[j] - ly, dz = pz[j] - lz;
            float d = dx * dx + dy * dy + dz * dz;
            float m = fminf(md[j], d);
            md[j] = m;
            if (m > bv) { bv = m; bi = j * 1024 + t; }
        }
        // wave argmax reduce (64 lanes)
#pragma unroll
        for (int off = 32; off > 0; off >>= 1) {
            float ov = __shfl_xor(bv, off, 64);
            int   oi = __shfl_xor(bi, off, 64);
            if (ov > bv) { bv = ov; bi = oi; }
        }
        if ((t & 63) == 0) { s_val[t >> 6] = bv; s_idx[t >> 6] = bi; }
        __syncthreads();
        // all threads redundantly reduce the 16 wave winners (LDS broadcast reads)
        float fv = s_val[0];
        int   fi = s_idx[0];
#pragma unroll
        for (int k = 1; k < 16; ++k) {
            float v = s_val[k];
            int   ix = s_idx[k];
            if (v > fv) { fv = v; fi = ix; }
        }
        __syncthreads();  // protect s_val/s_idx for next iteration
        // broadcast load of winner's coords (single cache line, L2-resident)
        lx = X[3 * fi];
        ly = X[3 * fi + 1];
        lz = X[3 * fi + 2];
        if (t == 0) {
            out_newxyz[b * NPOINT * 3 + 3 * i]     = lx;
            out_newxyz[b * NPOINT * 3 + 3 * i + 1] = ly;
            out_newxyz[b * NPOINT * 3 + 3 * i + 2] = lz;
        }
    }
}

// ---------------------------------------------------------------------------
// Kernel 2: fused ball query + grouping + 3-layer MLP + max over samples.
// One wave per query point (4 waves / 256-thread block). Lane = sample slot.
// Weights read with wave-uniform indices -> scalar loads (K$ pipe).
// ---------------------------------------------------------------------------
__global__ __launch_bounds__(256, 2) void bq_mlp_kernel(
    const float* __restrict__ xyz, const float* __restrict__ feat,
    const float* __restrict__ W1, const float* __restrict__ b1,
    const float* __restrict__ W2, const float* __restrict__ b2,
    const float* __restrict__ W3, const float* __restrict__ b3,
    const float* __restrict__ newxyz, float* __restrict__ out) {
    const int wave = threadIdx.x >> 6;
    const int lane = threadIdx.x & 63;
    const int q = blockIdx.x * 4 + wave;   // 0..4095
    const int b = q >> 10;
    const int p = q & 1023;
    const float* X = xyz  + (size_t)b * N_PTS * 3;
    const float* F = feat + (size_t)b * N_PTS * 3;

    const float cx = newxyz[3 * q], cy = newxyz[3 * q + 1], cz = newxyz[3 * q + 2];

    __shared__ float g[4][NSAMPLE][6];

    // --- ball query: first NSAMPLE points (in index order) with d2 < R2 ---
    int count = 0;
    for (int base = 0; base < N_PTS; base += 64) {
        int n = base + lane;
        float x = X[3 * n], y = X[3 * n + 1], z = X[3 * n + 2];
        float dx = x - cx, dy = y - cy, dz = z - cz;
        float d2 = dx * dx + dy * dy + dz * dz;
        bool in = d2 < R2;
        unsigned long long mask = __ballot(in);
        int slot = count + __popcll(mask & ((1ull << lane) - 1ull));
        if (in && slot < NSAMPLE) {
            float fx = F[3 * n], fy = F[3 * n + 1], fz = F[3 * n + 2];
            g[wave][slot][0] = dx; g[wave][slot][1] = dy; g[wave][slot][2] = dz;
            g[wave][slot][3] = fx; g[wave][slot][4] = fy; g[wave][slot][5] = fz;
        }
        count += __popcll(mask);
        if (count >= NSAMPLE) break;
    }
    asm volatile("s_waitcnt lgkmcnt(0)" ::: "memory");
    if (count == 0) {
        // no point in ball -> reference pads with index 0
        float x = X[0], y = X[1], z = X[2];
        g[wave][lane][0] = x - cx; g[wave][lane][1] = y - cy; g[wave][lane][2] = z - cz;
        g[wave][lane][3] = F[0];   g[wave][lane][4] = F[1];   g[wave][lane][5] = F[2];
    } else if (lane >= count) {
        // pad with the first in-ball point's values (slot 0)
        float v0 = g[wave][0][0], v1 = g[wave][0][1], v2 = g[wave][0][2];
        float v3 = g[wave][0][3], v4 = g[wave][0][4], v5 = g[wave][0][5];
        g[wave][lane][0] = v0; g[wave][lane][1] = v1; g[wave][lane][2] = v2;
        g[wave][lane][3] = v3; g[wave][lane][4] = v4; g[wave][lane][5] = v5;
    }
    asm volatile("s_waitcnt lgkmcnt(0)" ::: "memory");

    float gv[6];
#pragma unroll
    for (int k = 0; k < 6; ++k) gv[k] = g[wave][lane][k];

    // --- layer 1: 6 -> 64 ---
    float h1[64];
#pragma unroll
    for (int o = 0; o < 64; ++o) {
        float a = b1[o];
#pragma unroll
        for (int c = 0; c < 6; ++c) a += W1[o * 6 + c] * gv[c];
        h1[o] = fmaxf(a, 0.0f);
    }
    // --- layer 2: 64 -> 64 ---
    float h2[64];
#pragma unroll
    for (int o = 0; o < 64; ++o) {
        float a = b2[o];
#pragma unroll
        for (int c = 0; c < 64; ++c) a += W2[o * 64 + c] * h1[c];
        h2[o] = fmaxf(a, 0.0f);
    }
    // --- layer 3: 64 -> 128, fused with max over samples (lanes) ---
    float o0 = 0.0f, o1 = 0.0f;  // relu >= 0, so 0 is a safe identity for max
#pragma unroll
    for (int o = 0; o < 128; ++o) {
        float a = b3[o];
#pragma unroll
        for (int c = 0; c < 64; ++c) a += W3[o * 64 + c] * h2[c];
        a = fmaxf(a, 0.0f);
#pragma unroll
        for (int off = 32; off > 0; off >>= 1) a = fmaxf(a, __shfl_xor(a, off, 64));
        if (lane == (o & 63)) { if (o < 64) o0 = a; else o1 = a; }
    }
    // out[b][o][p], o = lane and lane+64
    out[(size_t)b * 128 * NPOINT + (size_t)lane        * NPOINT + p] = o0;
    out[(size_t)b * 128 * NPOINT + (size_t)(lane + 64) * NPOINT + p] = o1;
}

extern "C" void kernel_launch(void* const* d_in, const int* in_sizes, int n_in,
                              void* d_out, int out_size, void* d_ws, size_t ws_size,
                              hipStream_t stream) {
    const float* xyz  = (const float*)d_in[0];
    const float* feat = (const float*)d_in[1];
    const float* W1   = (const float*)d_in[2];
    const float* b1   = (const float*)d_in[3];
    const float* W2   = (const float*)d_in[4];
    const float* b2   = (const float*)d_in[5];
    const float* W3   = (const float*)d_in[6];
    const float* b3   = (const float*)d_in[7];
    float* out = (float*)d_out;

    // out layout: new_xyz (4*1024*3) then new_features (4*128*1024)
    float* out_newxyz = out;
    float* out_feat   = out + 4 * NPOINT * 3;

    fps_kernel<<<4, 1024, 0, stream>>>(xyz, out_newxyz);
    bq_mlp_kernel<<<1024, 256, 0, stream>>>(xyz, feat, W1, b1, W2, b2, W3, b3,
                                            out_newxyz, out_feat);
}

// Round 3
// 2081.609 us; speedup vs baseline: 1.2353x; 1.2353x over previous
//
#include <hip/hip_runtime.h>

#define N_PTS   16384
#define NPOINT  1024
#define NSAMPLE 64
#define R2 ((float)(0.3 * 0.3))

// ---------------------------------------------------------------------------
// Kernel 1: furthest point sampling. One block per batch, 1024 threads,
// 16 points per thread in registers. Value-only argmax in the hot loop;
// index resolved afterwards by bitwise-equality scan (exact, tie-safe via
// atomicMin = first-occurrence semantics, matching jnp.argmax).
// ---------------------------------------------------------------------------
__global__ __launch_bounds__(1024, 1) void fps_kernel(
    const float* __restrict__ xyz, float* __restrict__ out_newxyz) {
    const int b = blockIdx.x;
    const int t = threadIdx.x;
    const float* __restrict__ X = xyz + (size_t)b * N_PTS * 3;

    float px[16], py[16], pz[16], md[16];
#pragma unroll
    for (int j = 0; j < 16; ++j) {
        int n = j * 1024 + t;
        px[j] = X[3 * n];
        py[j] = X[3 * n + 1];
        pz[j] = X[3 * n + 2];
        md[j] = 1e10f;
    }

    __shared__ __align__(16) float s_val[16];
    __shared__ int s_win[2];
    if (t == 0) { s_win[0] = 0x7fffffff; s_win[1] = 0x7fffffff; }

    float lx = X[0], ly = X[1], lz = X[2];
    if (t == 0) {
        out_newxyz[b * NPOINT * 3 + 0] = lx;
        out_newxyz[b * NPOINT * 3 + 1] = ly;
        out_newxyz[b * NPOINT * 3 + 2] = lz;
    }
    __syncthreads();  // s_win init visible

    for (int i = 1; i < NPOINT; ++i) {
        // --- update mindist, track thread-local max value only ---
        float tv = -1.0f;
#pragma unroll
        for (int j = 0; j < 16; ++j) {
            float dx = px[j] - lx, dy = py[j] - ly, dz = pz[j] - lz;
            float d = dx * dx + dy * dy + dz * dz;
            float m = fminf(md[j], d);
            md[j] = m;
            tv = fmaxf(tv, m);
        }
        // --- wave max (value only) ---
        float wv = tv;
#pragma unroll
        for (int off = 32; off > 0; off >>= 1)
            wv = fmaxf(wv, __shfl_xor(wv, off, 64));
        if ((t & 63) == 0) s_val[t >> 6] = wv;
        __syncthreads();
        // --- redundant block max (16 values, float4 reads) ---
        const float4* sv4 = reinterpret_cast<const float4*>(s_val);
        float4 a0 = sv4[0], a1 = sv4[1], a2 = sv4[2], a3 = sv4[3];
        float f0 = fmaxf(fmaxf(a0.x, a0.y), fmaxf(a0.z, a0.w));
        float f1 = fmaxf(fmaxf(a1.x, a1.y), fmaxf(a1.z, a1.w));
        float f2 = fmaxf(fmaxf(a2.x, a2.y), fmaxf(a2.z, a2.w));
        float f3 = fmaxf(fmaxf(a3.x, a3.y), fmaxf(a3.z, a3.w));
        float fv = fmaxf(fmaxf(f0, f1), fmaxf(f2, f3));
        // --- winner resolves its index (fmax selects exactly, so bit-equal) ---
        if (tv == fv) {
            int cand = 0x7fffffff;
#pragma unroll
            for (int j = 15; j >= 0; --j)   // descending: final = smallest j
                cand = (md[j] == fv) ? (j * 1024 + t) : cand;
            atomicMin(&s_win[i & 1], cand);
        }
        __syncthreads();
        int fi = s_win[i & 1];
        if (t == 0) s_win[(i & 1) ^ 1] = 0x7fffffff;  // reset cell for next iter
        int fis = __builtin_amdgcn_readfirstlane(fi);
        const float* __restrict__ Xw = X + 3 * fis;   // uniform -> scalar loads
        lx = Xw[0]; ly = Xw[1]; lz = Xw[2];
        if (t == 0) {
            float* o = out_newxyz + b * NPOINT * 3 + 3 * i;
            o[0] = lx; o[1] = ly; o[2] = lz;
        }
    }
}

// ---------------------------------------------------------------------------
// Kernel 2: fused ball query + grouping + 3-layer MLP + max over samples.
// One wave per query. Ball query: lane = candidate. MLP: lane = out channel,
// weight rows in registers (phase-loaded to cap VGPR), activations ping-pong
// through LDS (broadcast reads). s-loops are runtime loops -> small I$ body.
// ---------------------------------------------------------------------------
__global__ __launch_bounds__(256, 2) void bq_mlp_kernel(
    const float* __restrict__ xyz, const float* __restrict__ feat,
    const float* __restrict__ W1, const float* __restrict__ b1,
    const float* __restrict__ W2, const float* __restrict__ b2,
    const float* __restrict__ W3, const float* __restrict__ b3,
    const float* __restrict__ newxyz, float* __restrict__ out) {
    const int wave = threadIdx.x >> 6;
    const int lane = threadIdx.x & 63;
    const int q = blockIdx.x * 4 + wave;   // 0..4095
    const int b = q >> 10;
    const int p = q & 1023;
    const float* __restrict__ X = xyz  + (size_t)b * N_PTS * 3;
    const float* __restrict__ F = feat + (size_t)b * N_PTS * 3;

    const float cx = newxyz[3 * q], cy = newxyz[3 * q + 1], cz = newxyz[3 * q + 2];

    __shared__ __align__(16) float g[4][NSAMPLE][8];
    __shared__ __align__(16) float h[4][NSAMPLE][64];

    // layer-1 weights (6 per lane) + biases
    float w1r[6];
#pragma unroll
    for (int k = 0; k < 6; ++k) w1r[k] = W1[lane * 6 + k];
    const float b1r = b1[lane];
    const float b2r = b2[lane];

    // --- ball query: first NSAMPLE points (index order) with d2 < R2 ---
    int count = 0;
    for (int base = 0; base < N_PTS; base += 64) {
        int n = base + lane;
        float x = X[3 * n], y = X[3 * n + 1], z = X[3 * n + 2];
        float dx = x - cx, dy = y - cy, dz = z - cz;
        float d2 = dx * dx + dy * dy + dz * dz;
        bool in = d2 < R2;
        unsigned long long mask = __ballot(in);
        int slot = count + __popcll(mask & ((1ull << lane) - 1ull));
        if (in && slot < NSAMPLE) {
            g[wave][slot][0] = dx; g[wave][slot][1] = dy; g[wave][slot][2] = dz;
            g[wave][slot][3] = F[3 * n]; g[wave][slot][4] = F[3 * n + 1];
            g[wave][slot][5] = F[3 * n + 2];
        }
        count += __popcll(mask);
        if (count >= NSAMPLE) break;
    }
    asm volatile("s_waitcnt lgkmcnt(0)" ::: "memory");
    if (count == 0) {
        float x = X[0], y = X[1], z = X[2];
        g[wave][lane][0] = x - cx; g[wave][lane][1] = y - cy; g[wave][lane][2] = z - cz;
        g[wave][lane][3] = F[0];   g[wave][lane][4] = F[1];   g[wave][lane][5] = F[2];
    } else if (lane >= count) {
        float v0 = g[wave][0][0], v1 = g[wave][0][1], v2 = g[wave][0][2];
        float v3 = g[wave][0][3], v4 = g[wave][0][4], v5 = g[wave][0][5];
        g[wave][lane][0] = v0; g[wave][lane][1] = v1; g[wave][lane][2] = v2;
        g[wave][lane][3] = v3; g[wave][lane][4] = v4; g[wave][lane][5] = v5;
    }
    __syncthreads();

    // --- phase A: layer 1 (6 -> 64), lane = output channel ---
    for (int s = 0; s < NSAMPLE; ++s) {
        const float4* g4 = reinterpret_cast<const float4*>(&g[wave][s][0]);
        float4 ga = g4[0], gb = g4[1];
        float a = fmaf(w1r[0], ga.x, b1r);
        a = fmaf(w1r[1], ga.y, a);
        a = fmaf(w1r[2], ga.z, a);
        a = fmaf(w1r[3], ga.w, a);
        a = fmaf(w1r[4], gb.x, a);
        a = fmaf(w1r[5], gb.y, a);
        h[wave][s][lane] = fmaxf(a, 0.0f);
    }
    __syncthreads();

    // --- load W2 row (64 regs) ---
    float w2r[64];
    {
        const float4* w4 = reinterpret_cast<const float4*>(W2 + (size_t)lane * 64);
#pragma unroll
        for (int cc = 0; cc < 16; ++cc) *reinterpret_cast<float4*>(&w2r[4 * cc]) = w4[cc];
    }

    // --- phase B: layer 2 (64 -> 64), in-place overwrite ---
#pragma unroll 2
    for (int s = 0; s < NSAMPLE; ++s) {
        float a0 = 0.f, a1 = 0.f, a2 = 0.f, a3 = 0.f;
        const float4* h4 = reinterpret_cast<const float4*>(&h[wave][s][0]);
#pragma unroll
        for (int cc = 0; cc < 16; ++cc) {
            float4 hv = h4[cc];
            a0 = fmaf(w2r[4 * cc + 0], hv.x, a0);
            a1 = fmaf(w2r[4 * cc + 1], hv.y, a1);
            a2 = fmaf(w2r[4 * cc + 2], hv.z, a2);
            a3 = fmaf(w2r[4 * cc + 3], hv.w, a3);
        }
        float v = fmaxf(b2r + ((a0 + a1) + (a2 + a3)), 0.0f);
        h[wave][s][lane] = v;   // same-wave in-order DS: safe after reads
    }
    __syncthreads();

    // --- load W3 rows lane and lane+64 (128 regs; w2r dead -> reused) ---
    float w3a[64], w3b[64];
    {
        const float4* wa = reinterpret_cast<const float4*>(W3 + (size_t)lane * 64);
        const float4* wb = reinterpret_cast<const float4*>(W3 + (size_t)(lane + 64) * 64);
#pragma unroll
        for (int cc = 0; cc < 16; ++cc) {
            *reinterpret_cast<float4*>(&w3a[4 * cc]) = wa[cc];
            *reinterpret_cast<float4*>(&w3b[4 * cc]) = wb[cc];
        }
    }
    const float b3r0 = b3[lane];
    const float b3r1 = b3[lane + 64];

    // --- phase C: layer 3 (64 -> 128) + max over samples ---
    float m0 = 0.0f, m1 = 0.0f;   // relu >= 0 so 0 is a safe max identity
#pragma unroll 2
    for (int s = 0; s < NSAMPLE; ++s) {
        float a0 = 0.f, a1 = 0.f, a2 = 0.f, a3 = 0.f;
        float c0 = 0.f, c1 = 0.f, c2 = 0.f, c3 = 0.f;
        const float4* h4 = reinterpret_cast<const float4*>(&h[wave][s][0]);
#pragma unroll
        for (int cc = 0; cc < 16; ++cc) {
            float4 hv = h4[cc];
            a0 = fmaf(w3a[4 * cc + 0], hv.x, a0);
            a1 = fmaf(w3a[4 * cc + 1], hv.y, a1);
            a2 = fmaf(w3a[4 * cc + 2], hv.z, a2);
            a3 = fmaf(w3a[4 * cc + 3], hv.w, a3);
            c0 = fmaf(w3b[4 * cc + 0], hv.x, c0);
            c1 = fmaf(w3b[4 * cc + 1], hv.y, c1);
            c2 = fmaf(w3b[4 * cc + 2], hv.z, c2);
            c3 = fmaf(w3b[4 * cc + 3], hv.w, c3);
        }
        float v0 = fmaxf(b3r0 + ((a0 + a1) + (a2 + a3)), 0.0f);
        float v1 = fmaxf(b3r1 + ((c0 + c1) + (c2 + c3)), 0.0f);
        m0 = fmaxf(m0, v0);
        m1 = fmaxf(m1, v1);
    }
    out[(size_t)b * 128 * NPOINT + (size_t)lane        * NPOINT + p] = m0;
    out[(size_t)b * 128 * NPOINT + (size_t)(lane + 64) * NPOINT + p] = m1;
}

extern "C" void kernel_launch(void* const* d_in, const int* in_sizes, int n_in,
                              void* d_out, int out_size, void* d_ws, size_t ws_size,
                              hipStream_t stream) {
    const float* xyz  = (const float*)d_in[0];
    const float* feat = (const float*)d_in[1];
    const float* W1   = (const float*)d_in[2];
    const float* b1   = (const float*)d_in[3];
    const float* W2   = (const float*)d_in[4];
    const float* b2   = (const float*)d_in[5];
    const float* W3   = (const float*)d_in[6];
    const float* b3   = (const float*)d_in[7];
    float* out = (float*)d_out;

    float* out_newxyz = out;
    float* out_feat   = out + 4 * NPOINT * 3;

    fps_kernel<<<4, 1024, 0, stream>>>(xyz, out_newxyz);
    bq_mlp_kernel<<<1024, 256, 0, stream>>>(xyz, feat, W1, b1, W2, b2, W3, b3,
                                            out_newxyz, out_feat);
}